// Round 5
// baseline (82.015 us; speedup 1.0000x reference)
//
#include <hip/hip_runtime.h>
#include <hip/hip_bf16.h>
#include <math.h>

// BahdanauAttention on MI355X (gfx950).
// query (16,64,1024) f32, keys (16,128,1024) f32, Wq/Wk (1024,1024) f32,
// la (1024), scalar (1), bias (1024). Outputs: context (16,64,1024) then
// scores (16,64,128), concatenated flat f32.
//
// K0 cast+prep: query/keys/Wq/Wk -> bf16 (RNE); la2 = 2*la_n, Sla = sum(la_n)
// K2 gemm:      aq = ALPHA*(q@Wq^T); ak = ALPHA*(k@Wk^T + bias)  [bf16 MFMA]
// K3 scores:    spart[h] = (h?0:Sla) - sum_{n in half h} la2[n]/(1+exp2(aq+ak))
//               grid (16,32,2) -> 4 waves/SIMD (round-4 fix: was 2, 18% occ)
// K4 ctx:       s = spart0+spart1; softmax; ctx = p@keys  (n-split, grid z=2)

#define ALPHA_2LOG2E 2.8853900817779268f
#define LOG2E 1.4426950408889634f

typedef __attribute__((ext_vector_type(8))) short short8;
typedef __attribute__((ext_vector_type(4))) float f32x4;

static __device__ __forceinline__ short f2bf(float f) {
    union { float f; unsigned u; } v; v.f = f;
    unsigned r = v.u + 0x7fffu + ((v.u >> 16) & 1u);   // round-nearest-even
    return (short)(r >> 16);
}

// ---------------- K0: fp32 -> bf16 cast, plus la prep in last block ----------------
// blocks: [0,512) query, [512,1536) keys, [1536,2048) Wq, [2048,2560) Wk, 2560 = la prep
__global__ __launch_bounds__(256) void cast_prep_kernel(
    const float* __restrict__ q, const float* __restrict__ k,
    const float* __restrict__ wq, const float* __restrict__ wk,
    short* __restrict__ qb, short* __restrict__ kb,
    short* __restrict__ wqb, short* __restrict__ wkb,
    const float* __restrict__ la, const float* __restrict__ scal,
    float* __restrict__ la2, float* __restrict__ sla)
{
    const int bid = blockIdx.x;
    if (bid == 2560) {   // la prep
        __shared__ float red[4];
        const int t = threadIdx.x, lane = t & 63, w = t >> 6;
        float ss = 0.f;
        for (int i = t; i < 1024; i += 256) { float v = la[i]; ss = fmaf(v, v, ss); }
        #pragma unroll
        for (int off = 32; off; off >>= 1) ss += __shfl_xor(ss, off, 64);
        if (lane == 0) red[w] = ss;
        __syncthreads();
        const float tot = red[0] + red[1] + red[2] + red[3];
        const float sc = scal[0] / sqrtf(tot);
        float s2 = 0.f;
        for (int i = t; i < 1024; i += 256) {
            float v = la[i] * sc;
            la2[i] = 2.f * v;
            s2 += v;
        }
        #pragma unroll
        for (int off = 32; off; off >>= 1) s2 += __shfl_xor(s2, off, 64);
        __syncthreads();
        if (lane == 0) red[w] = s2;
        __syncthreads();
        if (t == 0) sla[0] = red[0] + red[1] + red[2] + red[3];
        return;
    }
    const float* src; short* dst; int base;
    if (bid < 512)       { src = q;  dst = qb;  base = bid; }
    else if (bid < 1536) { src = k;  dst = kb;  base = bid - 512; }
    else if (bid < 2048) { src = wq; dst = wqb; base = bid - 1536; }
    else                 { src = wk; dst = wkb; base = bid - 2048; }
    const size_t i = ((size_t)base * 256 + threadIdx.x) * 8;
    float4 a = *reinterpret_cast<const float4*>(src + i);
    float4 b = *reinterpret_cast<const float4*>(src + i + 4);
    short8 o;
    o[0] = f2bf(a.x); o[1] = f2bf(a.y); o[2] = f2bf(a.z); o[3] = f2bf(a.w);
    o[4] = f2bf(b.x); o[5] = f2bf(b.y); o[6] = f2bf(b.z); o[7] = f2bf(b.w);
    *reinterpret_cast<short8*>(dst + i) = o;
}

// ---------------- K2: bf16 MFMA NT-GEMM (unchanged from round 3) ----------------
__global__ __launch_bounds__(256) void gemm_mfma_kernel(
    const short* __restrict__ qb, const short* __restrict__ kb,
    const short* __restrict__ wqb, const short* __restrict__ wkb,
    const float* __restrict__ bias,
    float* __restrict__ aq, float* __restrict__ ak)
{
    __shared__ short As[2][128][32];
    __shared__ short Bs[2][64][32];

    const int bx = blockIdx.x, by = blockIdx.y;
    const short* A; const short* W; float* C; int useBias; int bm;
    if (bx < 8) { A = qb; W = wqb; C = aq; useBias = 0; bm = bx * 128; }
    else        { A = kb; W = wkb; C = ak; useBias = 1; bm = (bx - 8) * 128; }
    const int bn = by * 64;

    const int t = threadIdx.x;
    const int lane = t & 63, wid = t >> 6;
    const int wr = wid >> 1, wc = wid & 1;
    const int fr = lane & 15, fg = lane >> 4;

    const int sRow = t >> 2, sSlot = t & 3;
    const short8* pA = (const short8*)(A + (size_t)bm * 1024);
    const short8* pB = (const short8*)(W + (size_t)bn * 1024);

    const f32x4 zero = {0.f, 0.f, 0.f, 0.f};
    f32x4 acc[4][2];
    #pragma unroll
    for (int mi = 0; mi < 4; ++mi)
        #pragma unroll
        for (int ni = 0; ni < 2; ++ni) acc[mi][ni] = zero;

    short8 rA0 = pA[(size_t)sRow * 128 + sSlot];
    short8 rA1 = pA[(size_t)(sRow + 64) * 128 + sSlot];
    short8 rB  = pB[(size_t)sRow * 128 + sSlot];
    *(short8*)&As[0][sRow][sSlot * 8]      = rA0;
    *(short8*)&As[0][sRow + 64][sSlot * 8] = rA1;
    *(short8*)&Bs[0][sRow][sSlot * 8]      = rB;
    rA0 = pA[(size_t)sRow * 128 + 4 + sSlot];
    rA1 = pA[(size_t)(sRow + 64) * 128 + 4 + sSlot];
    rB  = pB[(size_t)sRow * 128 + 4 + sSlot];
    asm volatile("s_waitcnt lgkmcnt(0)" ::: "memory");
    __builtin_amdgcn_s_barrier();
    asm volatile("" ::: "memory");

    #pragma unroll 1
    for (int kt = 0; kt < 32; ++kt) {
        const int cur = kt & 1;
        short8 af[4], bfr[2];
        #pragma unroll
        for (int mi = 0; mi < 4; ++mi)
            af[mi] = *(const short8*)&As[cur][wr * 64 + mi * 16 + fr][fg * 8];
        #pragma unroll
        for (int ni = 0; ni < 2; ++ni)
            bfr[ni] = *(const short8*)&Bs[cur][wc * 32 + ni * 16 + fr][fg * 8];
        if (kt < 31) {
            *(short8*)&As[cur ^ 1][sRow][sSlot * 8]      = rA0;
            *(short8*)&As[cur ^ 1][sRow + 64][sSlot * 8] = rA1;
            *(short8*)&Bs[cur ^ 1][sRow][sSlot * 8]      = rB;
        }
        if (kt < 30) {
            const int koff = (kt + 2) * 4 + sSlot;
            rA0 = pA[(size_t)sRow * 128 + koff];
            rA1 = pA[(size_t)(sRow + 64) * 128 + koff];
            rB  = pB[(size_t)sRow * 128 + koff];
        }
        #pragma unroll
        for (int mi = 0; mi < 4; ++mi)
            #pragma unroll
            for (int ni = 0; ni < 2; ++ni)
                acc[mi][ni] = __builtin_amdgcn_mfma_f32_16x16x32_bf16(
                    af[mi], bfr[ni], acc[mi][ni], 0, 0, 0);
        asm volatile("s_waitcnt lgkmcnt(0)" ::: "memory");
        __builtin_amdgcn_s_barrier();
        asm volatile("" ::: "memory");
    }

    float* Cb = C + (size_t)bm * 1024;
    float b0 = 0.f, b1 = 0.f;
    if (useBias) {
        b0 = bias[bn + wc * 32 + fr];
        b1 = bias[bn + wc * 32 + 16 + fr];
    }
    #pragma unroll
    for (int mi = 0; mi < 4; ++mi) {
        const int row0 = wr * 64 + mi * 16 + fg * 4;
        #pragma unroll
        for (int ni = 0; ni < 2; ++ni) {
            const int col = bn + wc * 32 + ni * 16 + fr;
            const float bb = ni ? b1 : b0;
            #pragma unroll
            for (int r = 0; r < 4; ++r)
                Cb[(size_t)(row0 + r) * 1024 + col] = (acc[mi][ni][r] + bb) * ALPHA_2LOG2E;
        }
    }
}

// ---------------- K3: scores partials (n-split for occupancy) ----------------
// grid (16, 32, 2): block -> (batch, q-pair, n-half). Wave w: k in [32w,32w+32).
// Lane owns n = h*512 + j*64 + lane, j=0..7.
// spart[h][b*64+q][k] = (h?0:Sla) - sum_{n in half} la2[n]/(1+exp2(aq+ak))
__global__ __launch_bounds__(256) void scores_kernel(
    const float* __restrict__ aq, const float* __restrict__ ak,
    const float* __restrict__ la2, const float* __restrict__ sla,
    float* __restrict__ spart)
{
    const int b = blockIdx.x;
    const int q0 = blockIdx.y << 1;
    const int h = blockIdx.z;
    const int t = threadIdx.x, w = t >> 6, lane = t & 63;
    const int nb = (h << 9) + lane;

    float la2r[8], aq0r[8], aq1r[8];
    const float* aq0p = aq + ((size_t)((b << 6) + q0) << 10) + nb;
    #pragma unroll
    for (int j = 0; j < 8; ++j) {
        la2r[j] = la2[nb + (j << 6)];
        aq0r[j] = aq0p[j << 6];
        aq1r[j] = aq0p[1024 + (j << 6)];
    }
    const float base = h ? 0.f : sla[0];

    const float* akb = ak + ((size_t)(b << 7) << 10) + nb;
    float* sp = spart + ((size_t)h << 17) + ((size_t)((b << 6) + q0) << 7);

    #pragma unroll 1
    for (int kk = 0; kk < 32; ++kk) {
        const int k = (w << 5) + kk;
        const float* akrow = akb + ((size_t)k << 10);
        float acc0 = 0.f, acc1 = 0.f;
        #pragma unroll
        for (int j = 0; j < 8; ++j) {
            float akv = akrow[j << 6];
            float r0 = __builtin_amdgcn_rcpf(1.f + __builtin_amdgcn_exp2f(aq0r[j] + akv));
            float r1 = __builtin_amdgcn_rcpf(1.f + __builtin_amdgcn_exp2f(aq1r[j] + akv));
            acc0 = fmaf(la2r[j], r0, acc0);
            acc1 = fmaf(la2r[j], r1, acc1);
        }
        #pragma unroll
        for (int off = 32; off; off >>= 1) {
            acc0 += __shfl_xor(acc0, off, 64);
            acc1 += __shfl_xor(acc1, off, 64);
        }
        if (lane == 0) {
            sp[k] = base - acc0;
            sp[128 + k] = base - acc1;
        }
    }
}

// ---------------- K4: softmax + context (n-split) ----------------
// grid (16, 32, 2): block -> (batch, q-pair, n-half of context cols).
// Softmax computed redundantly in both halves (identical fp32 -> same bits);
// h==0 writes out_scores. Each thread: both q-rows x 2 cols (keys shared).
__global__ __launch_bounds__(256) void ctx_kernel(
    const float* __restrict__ spart, const float* __restrict__ keys,
    float* __restrict__ ctx, float* __restrict__ out_scores)
{
    const int b = blockIdx.x;
    const int q0 = blockIdx.y << 1;
    const int h = blockIdx.z;
    const int t = threadIdx.x, w = t >> 6, lane = t & 63;
    __shared__ float p_s[2][128];

    const float* sp0 = spart + ((size_t)((b << 6) + q0) << 7);
    const float* sp1 = sp0 + (1 << 17);

    if (w < 2) {
        const float* r0p = sp0 + (w << 7);
        const float* r1p = sp1 + (w << 7);
        float s0 = r0p[lane] + r1p[lane];
        float s1 = r0p[lane + 64] + r1p[lane + 64];
        float m = fmaxf(s0, s1);
        #pragma unroll
        for (int off = 32; off; off >>= 1) m = fmaxf(m, __shfl_xor(m, off, 64));
        float e0 = __builtin_amdgcn_exp2f((s0 - m) * LOG2E);
        float e1 = __builtin_amdgcn_exp2f((s1 - m) * LOG2E);
        float s = e0 + e1;
        #pragma unroll
        for (int off = 32; off; off >>= 1) s += __shfl_xor(s, off, 64);
        float inv = __builtin_amdgcn_rcpf(s);
        float p0 = e0 * inv, p1 = e1 * inv;
        p_s[w][lane] = p0;
        p_s[w][lane + 64] = p1;
        if (h == 0) {
            float* os = out_scores + (size_t)((b << 6) + q0 + w) * 128;
            os[lane] = p0;
            os[lane + 64] = p1;
        }
    }
    __syncthreads();

    // context: thread t -> cols n0,n0+1 for both q-rows
    const int n0 = (h << 9) + (t << 1);
    const float* kb = keys + ((size_t)(b << 7) << 10) + n0;
    float c00 = 0.f, c01 = 0.f, c10 = 0.f, c11 = 0.f;
    #pragma unroll 4
    for (int k = 0; k < 128; ++k) {
        float2 kv = *reinterpret_cast<const float2*>(kb + ((size_t)k << 10));
        float p0 = p_s[0][k], p1 = p_s[1][k];
        c00 = fmaf(p0, kv.x, c00); c01 = fmaf(p0, kv.y, c01);
        c10 = fmaf(p1, kv.x, c10); c11 = fmaf(p1, kv.y, c11);
    }
    float* cp = ctx + ((size_t)((b << 6) + q0) << 10) + n0;
    float2 o0 = {c00, c01}, o1 = {c10, c11};
    *reinterpret_cast<float2*>(cp) = o0;
    *reinterpret_cast<float2*>(cp + 1024) = o1;
}

extern "C" void kernel_launch(void* const* d_in, const int* in_sizes, int n_in,
                              void* d_out, int out_size, void* d_ws, size_t ws_size,
                              hipStream_t stream) {
    const float* query  = (const float*)d_in[0];
    const float* keys   = (const float*)d_in[1];
    const float* Wq     = (const float*)d_in[2];
    const float* Wk     = (const float*)d_in[3];
    const float* la     = (const float*)d_in[4];
    const float* scal   = (const float*)d_in[5];
    const float* bias   = (const float*)d_in[6];

    float* ws  = (float*)d_ws;
    float* aq  = ws;                        // 1M f32 (4 MB)
    float* ak  = ws + (1u << 20);           // 2M f32 (8 MB)
    float* la2 = ak + (2u << 20);           // 1024 f32
    float* sla = la2 + 1024;                // 1 f32
    short* qb  = (short*)(ws + 3 * 1048576 + 2048);  // 1M bf16
    short* kb  = qb + 1048576;                       // 2M bf16
    short* wqb = kb + 2097152;                       // 1M bf16
    short* wkb = wqb + 1048576;                      // 1M bf16
    // spart aliases wqb region (dead after gemm): 2*16*64*128 = 262144 f32 (1 MB)
    float* spart = (float*)wqb;

    float* ctx        = (float*)d_out;
    float* out_scores = ctx + (size_t)16 * 64 * 1024;

    cast_prep_kernel<<<2561, 256, 0, stream>>>(query, keys, Wq, Wk, qb, kb, wqb, wkb,
                                               la, scal, la2, sla);
    gemm_mfma_kernel<<<dim3(24, 16), 256, 0, stream>>>(qb, kb, wqb, wkb, bias, aq, ak);
    scores_kernel<<<dim3(16, 32, 2), 256, 0, stream>>>(aq, ak, la2, sla, spart);
    ctx_kernel<<<dim3(16, 32, 2), 256, 0, stream>>>(spart, keys, ctx, out_scores);
}

// Round 6
// 78.082 us; speedup vs baseline: 1.0504x; 1.0504x over previous
//
#include <hip/hip_runtime.h>
#include <hip/hip_bf16.h>
#include <math.h>

// BahdanauAttention on MI355X (gfx950).
// query (16,64,1024) f32, keys (16,128,1024) f32, Wq/Wk (1024,1024) f32,
// la (1024), scalar (1), bias (1024). Outputs: context (16,64,1024) then
// scores (16,64,128), concatenated flat f32.
//
// Round-6 structure (k-major scores; butterfly-free hot loop):
//  K0 cast+prep: q/k/Wq/Wk -> bf16; la2 = 2*la_n, Sla = sum(la_n)
//  K1 gemm:  aq[q][n]  = ALPHA*(query@Wq^T)            (M=1024, N=1024)
//            akT[n][bk] = ALPHA*(Wk@keys^T + bias[n])  (M=1024, N=2048)
//  K2 fused: per (batch, 4 q-rows): lanes own k (lane, lane+64); waves split n;
//            scores = Sla - sum_n la2[n]/(1+exp2(aq+akT)); LDS wave-reduce;
//            in-lane softmax; fp32 context vs keys. No cross-lane in hot loop.

#define ALPHA_2LOG2E 2.8853900817779268f
#define LOG2E 1.4426950408889634f

typedef __attribute__((ext_vector_type(8))) short short8;
typedef __attribute__((ext_vector_type(4))) float f32x4;

static __device__ __forceinline__ short f2bf(float f) {
    union { float f; unsigned u; } v; v.f = f;
    unsigned r = v.u + 0x7fffu + ((v.u >> 16) & 1u);   // round-nearest-even
    return (short)(r >> 16);
}

// ---------------- K0: fp32 -> bf16 cast, plus la prep in last block ----------------
__global__ __launch_bounds__(256) void cast_prep_kernel(
    const float* __restrict__ q, const float* __restrict__ k,
    const float* __restrict__ wq, const float* __restrict__ wk,
    short* __restrict__ qb, short* __restrict__ kb,
    short* __restrict__ wqb, short* __restrict__ wkb,
    const float* __restrict__ la, const float* __restrict__ scal,
    float* __restrict__ la2, float* __restrict__ sla)
{
    const int bid = blockIdx.x;
    if (bid == 2560) {   // la prep
        __shared__ float red[4];
        const int t = threadIdx.x, lane = t & 63, w = t >> 6;
        float ss = 0.f;
        for (int i = t; i < 1024; i += 256) { float v = la[i]; ss = fmaf(v, v, ss); }
        #pragma unroll
        for (int off = 32; off; off >>= 1) ss += __shfl_xor(ss, off, 64);
        if (lane == 0) red[w] = ss;
        __syncthreads();
        const float tot = red[0] + red[1] + red[2] + red[3];
        const float sc = scal[0] / sqrtf(tot);
        float s2 = 0.f;
        for (int i = t; i < 1024; i += 256) {
            float v = la[i] * sc;
            la2[i] = 2.f * v;
            s2 += v;
        }
        #pragma unroll
        for (int off = 32; off; off >>= 1) s2 += __shfl_xor(s2, off, 64);
        __syncthreads();
        if (lane == 0) red[w] = s2;
        __syncthreads();
        if (t == 0) sla[0] = red[0] + red[1] + red[2] + red[3];
        return;
    }
    const float* src; short* dst; int base;
    if (bid < 512)       { src = q;  dst = qb;  base = bid; }
    else if (bid < 1536) { src = k;  dst = kb;  base = bid - 512; }
    else if (bid < 2048) { src = wq; dst = wqb; base = bid - 1536; }
    else                 { src = wk; dst = wkb; base = bid - 2048; }
    const size_t i = ((size_t)base * 256 + threadIdx.x) * 8;
    float4 a = *reinterpret_cast<const float4*>(src + i);
    float4 b = *reinterpret_cast<const float4*>(src + i + 4);
    short8 o;
    o[0] = f2bf(a.x); o[1] = f2bf(a.y); o[2] = f2bf(a.z); o[3] = f2bf(a.w);
    o[4] = f2bf(b.x); o[5] = f2bf(b.y); o[6] = f2bf(b.z); o[7] = f2bf(b.w);
    *reinterpret_cast<short8*>(dst + i) = o;
}

// ---------------- K1: bf16 MFMA NT-GEMM ----------------
// bid < 128 : aq  = ALPHA*(qb @ wqb^T),  C 1024x1024 (ldc 1024), no bias
// bid >= 128: akT = ALPHA*(wkb @ kb^T + bias[row]), C 1024x2048 (ldc 2048)
__global__ __launch_bounds__(256) void gemm_mfma_kernel(
    const short* __restrict__ qb, const short* __restrict__ kb,
    const short* __restrict__ wqb, const short* __restrict__ wkb,
    const float* __restrict__ bias,
    float* __restrict__ aq, float* __restrict__ akT)
{
    __shared__ short As[2][128][32];
    __shared__ short Bs[2][64][32];

    const int bid = blockIdx.x;
    const short* A; const short* W; float* C; int useBias, bm, bn, ldc;
    if (bid < 128) {
        A = qb;  W = wqb; C = aq;  useBias = 0; ldc = 1024;
        bm = (bid & 7) * 128; bn = (bid >> 3) * 64;
    } else {
        int b2 = bid - 128;
        A = wkb; W = kb;  C = akT; useBias = 1; ldc = 2048;
        bm = (b2 & 7) * 128; bn = (b2 >> 3) * 64;
    }

    const int t = threadIdx.x;
    const int lane = t & 63, wid = t >> 6;
    const int wr = wid >> 1, wc = wid & 1;
    const int fr = lane & 15, fg = lane >> 4;

    const int sRow = t >> 2, sSlot = t & 3;
    const short8* pA = (const short8*)(A + (size_t)bm * 1024);
    const short8* pB = (const short8*)(W + (size_t)bn * 1024);

    const f32x4 zero = {0.f, 0.f, 0.f, 0.f};
    f32x4 acc[4][2];
    #pragma unroll
    for (int mi = 0; mi < 4; ++mi)
        #pragma unroll
        for (int ni = 0; ni < 2; ++ni) acc[mi][ni] = zero;

    short8 rA0 = pA[(size_t)sRow * 128 + sSlot];
    short8 rA1 = pA[(size_t)(sRow + 64) * 128 + sSlot];
    short8 rB  = pB[(size_t)sRow * 128 + sSlot];
    *(short8*)&As[0][sRow][sSlot * 8]      = rA0;
    *(short8*)&As[0][sRow + 64][sSlot * 8] = rA1;
    *(short8*)&Bs[0][sRow][sSlot * 8]      = rB;
    rA0 = pA[(size_t)sRow * 128 + 4 + sSlot];
    rA1 = pA[(size_t)(sRow + 64) * 128 + 4 + sSlot];
    rB  = pB[(size_t)sRow * 128 + 4 + sSlot];
    asm volatile("s_waitcnt lgkmcnt(0)" ::: "memory");
    __builtin_amdgcn_s_barrier();
    asm volatile("" ::: "memory");

    #pragma unroll 1
    for (int kt = 0; kt < 32; ++kt) {
        const int cur = kt & 1;
        short8 af[4], bfr[2];
        #pragma unroll
        for (int mi = 0; mi < 4; ++mi)
            af[mi] = *(const short8*)&As[cur][wr * 64 + mi * 16 + fr][fg * 8];
        #pragma unroll
        for (int ni = 0; ni < 2; ++ni)
            bfr[ni] = *(const short8*)&Bs[cur][wc * 32 + ni * 16 + fr][fg * 8];
        if (kt < 31) {
            *(short8*)&As[cur ^ 1][sRow][sSlot * 8]      = rA0;
            *(short8*)&As[cur ^ 1][sRow + 64][sSlot * 8] = rA1;
            *(short8*)&Bs[cur ^ 1][sRow][sSlot * 8]      = rB;
        }
        if (kt < 30) {
            const int koff = (kt + 2) * 4 + sSlot;
            rA0 = pA[(size_t)sRow * 128 + koff];
            rA1 = pA[(size_t)(sRow + 64) * 128 + koff];
            rB  = pB[(size_t)sRow * 128 + koff];
        }
        #pragma unroll
        for (int mi = 0; mi < 4; ++mi)
            #pragma unroll
            for (int ni = 0; ni < 2; ++ni)
                acc[mi][ni] = __builtin_amdgcn_mfma_f32_16x16x32_bf16(
                    af[mi], bfr[ni], acc[mi][ni], 0, 0, 0);
        asm volatile("s_waitcnt lgkmcnt(0)" ::: "memory");
        __builtin_amdgcn_s_barrier();
        asm volatile("" ::: "memory");
    }

    // C/D: col=lane&15, row=(lane>>4)*4+reg  [m89-verified]
    float* Cb = C + (size_t)bm * ldc;
    #pragma unroll
    for (int mi = 0; mi < 4; ++mi) {
        const int row0 = wr * 64 + mi * 16 + fg * 4;
        float brow[4] = {0.f, 0.f, 0.f, 0.f};
        if (useBias) {
            #pragma unroll
            for (int r = 0; r < 4; ++r) brow[r] = bias[bm + row0 + r];
        }
        #pragma unroll
        for (int ni = 0; ni < 2; ++ni) {
            const int col = bn + wc * 32 + ni * 16 + fr;
            #pragma unroll
            for (int r = 0; r < 4; ++r)
                Cb[(size_t)(row0 + r) * ldc + col] = (acc[mi][ni][r] + brow[r]) * ALPHA_2LOG2E;
        }
    }
}

// ---------------- K2: fused scores + softmax + context (k-major) ----------------
// grid (16 batch, 16 q-quads), 512 threads (8 waves). Lane owns k=lane, lane+64.
// Wave w accumulates n in [128w, 128w+128); LDS reduce; wave q<4 does softmax
// for row q; all waves then do context (thread -> 2 n-cols x 4 q-rows).
__global__ __launch_bounds__(512) void fused_kernel(
    const float* __restrict__ aq, const float* __restrict__ akT,
    const float* __restrict__ la2, const float* __restrict__ sla,
    const float* __restrict__ keys,
    float* __restrict__ ctx, float* __restrict__ out_scores)
{
    const int b = blockIdx.x;
    const int q0 = blockIdx.y << 2;
    const int t = threadIdx.x;
    const int w = t >> 6, lane = t & 63;

    __shared__ float aqs[4][1024];      // 16 KB
    __shared__ float pacc[8][4][128];   // 16 KB
    __shared__ float p_s[4][128];       // 2 KB

    // stage the 4 aq rows (already ALPHA-scaled)
    {
        const int row = t >> 7, n0 = (t & 127) << 3;
        const float* gp = aq + ((size_t)((b << 6) + q0 + row) << 10) + n0;
        float4 v0 = *reinterpret_cast<const float4*>(gp);
        float4 v1 = *reinterpret_cast<const float4*>(gp + 4);
        *reinterpret_cast<float4*>(&aqs[row][n0]) = v0;
        *reinterpret_cast<float4*>(&aqs[row][n0 + 4]) = v1;
    }
    __syncthreads();

    // scores partials: this wave's n-range
    float acc[4][2];
    #pragma unroll
    for (int q = 0; q < 4; ++q) { acc[q][0] = 0.f; acc[q][1] = 0.f; }

    const float* akb = akT + (b << 7) + lane;   // [n][b*128 + lane], row stride 2048
    const int nbase = w << 7;
    #pragma unroll 4
    for (int n = 0; n < 128; ++n) {
        const int nn = nbase + n;
        const float a0 = akb[(size_t)nn << 11];
        const float a1 = akb[((size_t)nn << 11) + 64];
        const float l2 = la2[nn];               // lane-uniform -> s_load
        #pragma unroll
        for (int q = 0; q < 4; ++q) {
            const float aqv = aqs[q][nn];       // LDS broadcast
            const float r0 = __builtin_amdgcn_rcpf(1.f + __builtin_amdgcn_exp2f(aqv + a0));
            const float r1 = __builtin_amdgcn_rcpf(1.f + __builtin_amdgcn_exp2f(aqv + a1));
            acc[q][0] = fmaf(l2, r0, acc[q][0]);
            acc[q][1] = fmaf(l2, r1, acc[q][1]);
        }
    }
    #pragma unroll
    for (int q = 0; q < 4; ++q) {
        pacc[w][q][lane]      = acc[q][0];
        pacc[w][q][lane + 64] = acc[q][1];
    }
    __syncthreads();

    // softmax: wave w<4 handles q-row w (scores already in lane=k layout)
    if (w < 4) {
        const float Sla = sla[0];
        float s0 = 0.f, s1 = 0.f;
        #pragma unroll
        for (int ww = 0; ww < 8; ++ww) {
            s0 += pacc[ww][w][lane];
            s1 += pacc[ww][w][lane + 64];
        }
        s0 = Sla - s0; s1 = Sla - s1;
        float m = fmaxf(s0, s1);
        #pragma unroll
        for (int off = 32; off; off >>= 1) m = fmaxf(m, __shfl_xor(m, off, 64));
        float e0 = __builtin_amdgcn_exp2f((s0 - m) * LOG2E);
        float e1 = __builtin_amdgcn_exp2f((s1 - m) * LOG2E);
        float s = e0 + e1;
        #pragma unroll
        for (int off = 32; off; off >>= 1) s += __shfl_xor(s, off, 64);
        const float inv = __builtin_amdgcn_rcpf(s);
        const float p0 = e0 * inv, p1 = e1 * inv;
        p_s[w][lane] = p0;
        p_s[w][lane + 64] = p1;
        float* os = out_scores + ((size_t)((b << 6) + q0 + w) << 7);
        os[lane] = p0;
        os[lane + 64] = p1;
    }
    __syncthreads();

    // context: thread t -> cols n0,n0+1 for all 4 q-rows
    const int n0 = t << 1;
    const float* kb = keys + ((size_t)(b << 7) << 10) + n0;
    float c[4][2];
    #pragma unroll
    for (int q = 0; q < 4; ++q) { c[q][0] = 0.f; c[q][1] = 0.f; }
    #pragma unroll 4
    for (int k = 0; k < 128; ++k) {
        const float2 kv = *reinterpret_cast<const float2*>(kb + ((size_t)k << 10));
        #pragma unroll
        for (int q = 0; q < 4; ++q) {
            const float p = p_s[q][k];          // LDS broadcast
            c[q][0] = fmaf(p, kv.x, c[q][0]);
            c[q][1] = fmaf(p, kv.y, c[q][1]);
        }
    }
    #pragma unroll
    for (int q = 0; q < 4; ++q) {
        float2 o = {c[q][0], c[q][1]};
        *reinterpret_cast<float2*>(ctx + ((size_t)((b << 6) + q0 + q) << 10) + n0) = o;
    }
}

extern "C" void kernel_launch(void* const* d_in, const int* in_sizes, int n_in,
                              void* d_out, int out_size, void* d_ws, size_t ws_size,
                              hipStream_t stream) {
    const float* query  = (const float*)d_in[0];
    const float* keys   = (const float*)d_in[1];
    const float* Wq     = (const float*)d_in[2];
    const float* Wk     = (const float*)d_in[3];
    const float* la     = (const float*)d_in[4];
    const float* scal   = (const float*)d_in[5];
    const float* bias   = (const float*)d_in[6];

    float* ws  = (float*)d_ws;
    float* aq  = ws;                        // 1M f32 (4 MB), [1024 q][1024 n]
    float* akT = ws + (1u << 20);           // 2M f32 (8 MB), [1024 n][2048 bk]
    float* la2 = akT + (2u << 20);          // 1024 f32
    float* sla = la2 + 1024;                // 1 f32
    short* qb  = (short*)(ws + 3 * 1048576 + 2048);  // 1M bf16
    short* kb  = qb + 1048576;                       // 2M bf16
    short* wqb = kb + 2097152;                       // 1M bf16
    short* wkb = wqb + 1048576;                      // 1M bf16

    float* ctx        = (float*)d_out;
    float* out_scores = ctx + (size_t)16 * 64 * 1024;

    cast_prep_kernel<<<2561, 256, 0, stream>>>(query, keys, Wq, Wk, qb, kb, wqb, wkb,
                                               la, scal, la2, sla);
    gemm_mfma_kernel<<<384, 256, 0, stream>>>(qb, kb, wqb, wkb, bias, aq, akT);
    fused_kernel<<<dim3(16, 16), 512, 0, stream>>>(aq, akT, la2, sla, keys, ctx, out_scores);
}

// Round 7
// 72.169 us; speedup vs baseline: 1.1364x; 1.0819x over previous
//
#include <hip/hip_runtime.h>
#include <hip/hip_bf16.h>
#include <math.h>

// BahdanauAttention on MI355X (gfx950).
// query (16,64,1024) f32, keys (16,128,1024) f32, Wq/Wk (1024,1024) f32,
// la (1024), scalar (1), bias (1024). Outputs: context (16,64,1024) then
// scores (16,64,128), concatenated flat f32.
//
// Round-7: k-major fused kernel at 4 waves/SIMD (was 2), LDS la2, float2 akT.
//  K0 cast+prep: q/k/Wq/Wk -> bf16; la2 = 2*la_n, Sla = sum(la_n)
//  K1 gemm:  aq[q][n]  = ALPHA*(query@Wq^T)            (M=1024, N=1024)
//            akT[n][bk] = ALPHA*(Wk@keys^T + bias[n])  (M=1024, N=2048)
//  K2 fused: per (batch, 2 q-rows): lane owns k={2l,2l+1}; waves split n 8-way;
//            scores = Sla - sum_n la2[n]/(1+exp2(aq+akT)); LDS reduce;
//            in-lane softmax; fp32 context vs keys.

#define ALPHA_2LOG2E 2.8853900817779268f
#define LOG2E 1.4426950408889634f

typedef __attribute__((ext_vector_type(8))) short short8;
typedef __attribute__((ext_vector_type(4))) float f32x4;

static __device__ __forceinline__ short f2bf(float f) {
    union { float f; unsigned u; } v; v.f = f;
    unsigned r = v.u + 0x7fffu + ((v.u >> 16) & 1u);   // round-nearest-even
    return (short)(r >> 16);
}

// ---------------- K0: fp32 -> bf16 cast, plus la prep in last block ----------------
__global__ __launch_bounds__(256) void cast_prep_kernel(
    const float* __restrict__ q, const float* __restrict__ k,
    const float* __restrict__ wq, const float* __restrict__ wk,
    short* __restrict__ qb, short* __restrict__ kb,
    short* __restrict__ wqb, short* __restrict__ wkb,
    const float* __restrict__ la, const float* __restrict__ scal,
    float* __restrict__ la2, float* __restrict__ sla)
{
    const int bid = blockIdx.x;
    if (bid == 2560) {   // la prep
        __shared__ float red[4];
        const int t = threadIdx.x, lane = t & 63, w = t >> 6;
        float ss = 0.f;
        for (int i = t; i < 1024; i += 256) { float v = la[i]; ss = fmaf(v, v, ss); }
        #pragma unroll
        for (int off = 32; off; off >>= 1) ss += __shfl_xor(ss, off, 64);
        if (lane == 0) red[w] = ss;
        __syncthreads();
        const float tot = red[0] + red[1] + red[2] + red[3];
        const float sc = scal[0] / sqrtf(tot);
        float s2 = 0.f;
        for (int i = t; i < 1024; i += 256) {
            float v = la[i] * sc;
            la2[i] = 2.f * v;
            s2 += v;
        }
        #pragma unroll
        for (int off = 32; off; off >>= 1) s2 += __shfl_xor(s2, off, 64);
        __syncthreads();
        if (lane == 0) red[w] = s2;
        __syncthreads();
        if (t == 0) sla[0] = red[0] + red[1] + red[2] + red[3];
        return;
    }
    const float* src; short* dst; int base;
    if (bid < 512)       { src = q;  dst = qb;  base = bid; }
    else if (bid < 1536) { src = k;  dst = kb;  base = bid - 512; }
    else if (bid < 2048) { src = wq; dst = wqb; base = bid - 1536; }
    else                 { src = wk; dst = wkb; base = bid - 2048; }
    const size_t i = ((size_t)base * 256 + threadIdx.x) * 8;
    float4 a = *reinterpret_cast<const float4*>(src + i);
    float4 b = *reinterpret_cast<const float4*>(src + i + 4);
    short8 o;
    o[0] = f2bf(a.x); o[1] = f2bf(a.y); o[2] = f2bf(a.z); o[3] = f2bf(a.w);
    o[4] = f2bf(b.x); o[5] = f2bf(b.y); o[6] = f2bf(b.z); o[7] = f2bf(b.w);
    *reinterpret_cast<short8*>(dst + i) = o;
}

// ---------------- K1: bf16 MFMA NT-GEMM ----------------
// bid < 128 : aq  = ALPHA*(qb @ wqb^T),  C 1024x1024 (ldc 1024), no bias
// bid >= 128: akT = ALPHA*(wkb @ kb^T + bias[row]), C 1024x2048 (ldc 2048)
__global__ __launch_bounds__(256) void gemm_mfma_kernel(
    const short* __restrict__ qb, const short* __restrict__ kb,
    const short* __restrict__ wqb, const short* __restrict__ wkb,
    const float* __restrict__ bias,
    float* __restrict__ aq, float* __restrict__ akT)
{
    __shared__ short As[2][128][32];
    __shared__ short Bs[2][64][32];

    const int bid = blockIdx.x;
    const short* A; const short* W; float* C; int useBias, bm, bn, ldc;
    if (bid < 128) {
        A = qb;  W = wqb; C = aq;  useBias = 0; ldc = 1024;
        bm = (bid & 7) * 128; bn = (bid >> 3) * 64;
    } else {
        int b2 = bid - 128;
        A = wkb; W = kb;  C = akT; useBias = 1; ldc = 2048;
        bm = (b2 & 7) * 128; bn = (b2 >> 3) * 64;
    }

    const int t = threadIdx.x;
    const int lane = t & 63, wid = t >> 6;
    const int wr = wid >> 1, wc = wid & 1;
    const int fr = lane & 15, fg = lane >> 4;

    const int sRow = t >> 2, sSlot = t & 3;
    const short8* pA = (const short8*)(A + (size_t)bm * 1024);
    const short8* pB = (const short8*)(W + (size_t)bn * 1024);

    const f32x4 zero = {0.f, 0.f, 0.f, 0.f};
    f32x4 acc[4][2];
    #pragma unroll
    for (int mi = 0; mi < 4; ++mi)
        #pragma unroll
        for (int ni = 0; ni < 2; ++ni) acc[mi][ni] = zero;

    short8 rA0 = pA[(size_t)sRow * 128 + sSlot];
    short8 rA1 = pA[(size_t)(sRow + 64) * 128 + sSlot];
    short8 rB  = pB[(size_t)sRow * 128 + sSlot];
    *(short8*)&As[0][sRow][sSlot * 8]      = rA0;
    *(short8*)&As[0][sRow + 64][sSlot * 8] = rA1;
    *(short8*)&Bs[0][sRow][sSlot * 8]      = rB;
    rA0 = pA[(size_t)sRow * 128 + 4 + sSlot];
    rA1 = pA[(size_t)(sRow + 64) * 128 + 4 + sSlot];
    rB  = pB[(size_t)sRow * 128 + 4 + sSlot];
    asm volatile("s_waitcnt lgkmcnt(0)" ::: "memory");
    __builtin_amdgcn_s_barrier();
    asm volatile("" ::: "memory");

    #pragma unroll 1
    for (int kt = 0; kt < 32; ++kt) {
        const int cur = kt & 1;
        short8 af[4], bfr[2];
        #pragma unroll
        for (int mi = 0; mi < 4; ++mi)
            af[mi] = *(const short8*)&As[cur][wr * 64 + mi * 16 + fr][fg * 8];
        #pragma unroll
        for (int ni = 0; ni < 2; ++ni)
            bfr[ni] = *(const short8*)&Bs[cur][wc * 32 + ni * 16 + fr][fg * 8];
        if (kt < 31) {
            *(short8*)&As[cur ^ 1][sRow][sSlot * 8]      = rA0;
            *(short8*)&As[cur ^ 1][sRow + 64][sSlot * 8] = rA1;
            *(short8*)&Bs[cur ^ 1][sRow][sSlot * 8]      = rB;
        }
        if (kt < 30) {
            const int koff = (kt + 2) * 4 + sSlot;
            rA0 = pA[(size_t)sRow * 128 + koff];
            rA1 = pA[(size_t)(sRow + 64) * 128 + koff];
            rB  = pB[(size_t)sRow * 128 + koff];
        }
        #pragma unroll
        for (int mi = 0; mi < 4; ++mi)
            #pragma unroll
            for (int ni = 0; ni < 2; ++ni)
                acc[mi][ni] = __builtin_amdgcn_mfma_f32_16x16x32_bf16(
                    af[mi], bfr[ni], acc[mi][ni], 0, 0, 0);
        asm volatile("s_waitcnt lgkmcnt(0)" ::: "memory");
        __builtin_amdgcn_s_barrier();
        asm volatile("" ::: "memory");
    }

    // C/D: col=lane&15, row=(lane>>4)*4+reg  [m89-verified]
    float* Cb = C + (size_t)bm * ldc;
    #pragma unroll
    for (int mi = 0; mi < 4; ++mi) {
        const int row0 = wr * 64 + mi * 16 + fg * 4;
        float brow[4] = {0.f, 0.f, 0.f, 0.f};
        if (useBias) {
            #pragma unroll
            for (int r = 0; r < 4; ++r) brow[r] = bias[bm + row0 + r];
        }
        #pragma unroll
        for (int ni = 0; ni < 2; ++ni) {
            const int col = bn + wc * 32 + ni * 16 + fr;
            #pragma unroll
            for (int r = 0; r < 4; ++r)
                Cb[(size_t)(row0 + r) * ldc + col] = (acc[mi][ni][r] + brow[r]) * ALPHA_2LOG2E;
        }
    }
}

// ---------------- K2: fused scores + softmax + context (k-major, 2q/block) ----------------
// grid (16 batch, 32 q-pairs), 512 threads (8 waves) -> 512 blocks, 16 waves/CU.
// Lane owns k = {2*lane, 2*lane+1} (one float2 akT load per n).
// Wave w accumulates n in [128w, 128w+128); LDS reduce; waves 0/1 softmax;
// all waves context (thread -> 2 n-cols x 2 q-rows).
__global__ __launch_bounds__(512) void fused_kernel(
    const float* __restrict__ aq, const float* __restrict__ akT,
    const float* __restrict__ la2, const float* __restrict__ sla,
    const float* __restrict__ keys,
    float* __restrict__ ctx, float* __restrict__ out_scores)
{
    const int b = blockIdx.x;
    const int q0 = blockIdx.y << 1;
    const int t = threadIdx.x;
    const int w = t >> 6, lane = t & 63;

    __shared__ float aqs[2][1024];      // 8 KB
    __shared__ float la2s[1024];        // 4 KB
    __shared__ float pacc[8][2][128];   // 8 KB
    __shared__ float p_s[2][128];       // 1 KB

    // stage the 2 aq rows (ALPHA-scaled) + la2
    {
        const int row = t >> 8, n0 = (t & 255) << 2;
        const float* gp = aq + ((size_t)((b << 6) + q0 + row) << 10) + n0;
        *reinterpret_cast<float4*>(&aqs[row][n0]) = *reinterpret_cast<const float4*>(gp);
        const int i2 = t << 1;
        *reinterpret_cast<float2*>(&la2s[i2]) = *reinterpret_cast<const float2*>(la2 + i2);
    }
    __syncthreads();

    // scores partials: this wave's n-range; zero cross-lane ops
    float acc[2][2];
    acc[0][0] = acc[0][1] = acc[1][0] = acc[1][1] = 0.f;

    const float* akb = akT + (b << 7) + (lane << 1);   // row stride 2048 floats
    const int nbase = w << 7;
    #pragma unroll 8
    for (int n = 0; n < 128; ++n) {
        const int nn = nbase + n;
        const float2 a = *reinterpret_cast<const float2*>(akb + ((size_t)nn << 11));
        const float l2 = la2s[nn];
        #pragma unroll
        for (int q = 0; q < 2; ++q) {
            const float aqv = aqs[q][nn];       // LDS broadcast
            const float r0 = __builtin_amdgcn_rcpf(1.f + __builtin_amdgcn_exp2f(aqv + a.x));
            const float r1 = __builtin_amdgcn_rcpf(1.f + __builtin_amdgcn_exp2f(aqv + a.y));
            acc[q][0] = fmaf(l2, r0, acc[q][0]);
            acc[q][1] = fmaf(l2, r1, acc[q][1]);
        }
    }
    #pragma unroll
    for (int q = 0; q < 2; ++q) {
        float2 v = {acc[q][0], acc[q][1]};
        *reinterpret_cast<float2*>(&pacc[w][q][lane << 1]) = v;
    }
    __syncthreads();

    // softmax: wave w<2 handles q-row w (lane holds k=2l,2l+1)
    if (w < 2) {
        const float Sla = sla[0];
        float s0 = 0.f, s1 = 0.f;
        #pragma unroll
        for (int ww = 0; ww < 8; ++ww) {
            float2 v = *reinterpret_cast<const float2*>(&pacc[ww][w][lane << 1]);
            s0 += v.x; s1 += v.y;
        }
        s0 = Sla - s0; s1 = Sla - s1;
        float m = fmaxf(s0, s1);
        #pragma unroll
        for (int off = 32; off; off >>= 1) m = fmaxf(m, __shfl_xor(m, off, 64));
        float e0 = __builtin_amdgcn_exp2f((s0 - m) * LOG2E);
        float e1 = __builtin_amdgcn_exp2f((s1 - m) * LOG2E);
        float s = e0 + e1;
        #pragma unroll
        for (int off = 32; off; off >>= 1) s += __shfl_xor(s, off, 64);
        const float inv = __builtin_amdgcn_rcpf(s);
        float2 p = {e0 * inv, e1 * inv};
        *reinterpret_cast<float2*>(&p_s[w][lane << 1]) = p;
        float* os = out_scores + ((size_t)((b << 6) + q0 + w) << 7);
        *reinterpret_cast<float2*>(os + (lane << 1)) = p;
    }
    __syncthreads();

    // context: thread t -> cols n0,n0+1 for both q-rows
    const int n0 = t << 1;
    const float* kb = keys + ((size_t)(b << 7) << 10) + n0;
    float c00 = 0.f, c01 = 0.f, c10 = 0.f, c11 = 0.f;
    #pragma unroll 4
    for (int k = 0; k < 128; ++k) {
        const float2 kv = *reinterpret_cast<const float2*>(kb + ((size_t)k << 10));
        const float p0 = p_s[0][k], p1 = p_s[1][k];
        c00 = fmaf(p0, kv.x, c00); c01 = fmaf(p0, kv.y, c01);
        c10 = fmaf(p1, kv.x, c10); c11 = fmaf(p1, kv.y, c11);
    }
    float* cp = ctx + ((size_t)((b << 6) + q0) << 10) + n0;
    float2 o0 = {c00, c01}, o1 = {c10, c11};
    *reinterpret_cast<float2*>(cp) = o0;
    *reinterpret_cast<float2*>(cp + 1024) = o1;
}

extern "C" void kernel_launch(void* const* d_in, const int* in_sizes, int n_in,
                              void* d_out, int out_size, void* d_ws, size_t ws_size,
                              hipStream_t stream) {
    const float* query  = (const float*)d_in[0];
    const float* keys   = (const float*)d_in[1];
    const float* Wq     = (const float*)d_in[2];
    const float* Wk     = (const float*)d_in[3];
    const float* la     = (const float*)d_in[4];
    const float* scal   = (const float*)d_in[5];
    const float* bias   = (const float*)d_in[6];

    float* ws  = (float*)d_ws;
    float* aq  = ws;                        // 1M f32 (4 MB), [1024 q][1024 n]
    float* akT = ws + (1u << 20);           // 2M f32 (8 MB), [1024 n][2048 bk]
    float* la2 = akT + (2u << 20);          // 1024 f32
    float* sla = la2 + 1024;                // 1 f32
    short* qb  = (short*)(ws + 3 * 1048576 + 2048);  // 1M bf16
    short* kb  = qb + 1048576;                       // 2M bf16
    short* wqb = kb + 2097152;                       // 1M bf16
    short* wkb = wqb + 1048576;                      // 1M bf16

    float* ctx        = (float*)d_out;
    float* out_scores = ctx + (size_t)16 * 64 * 1024;

    cast_prep_kernel<<<2561, 256, 0, stream>>>(query, keys, Wq, Wk, qb, kb, wqb, wkb,
                                               la, scal, la2, sla);
    gemm_mfma_kernel<<<384, 256, 0, stream>>>(qb, kb, wqb, wkb, bias, aq, akT);
    fused_kernel<<<dim3(16, 32), 512, 0, stream>>>(aq, akT, la2, sla, keys, ctx, out_scores);
}

// Round 8
// 65.846 us; speedup vs baseline: 1.2456x; 1.0960x over previous
//
#include <hip/hip_runtime.h>
#include <hip/hip_bf16.h>
#include <math.h>

// BahdanauAttention on MI355X (gfx950).
// query (16,64,1024) f32, keys (16,128,1024) f32, Wq/Wk (1024,1024) f32,
// la (1024), scalar (1), bias (1024). Outputs: context (16,64,1024) then
// scores (16,64,128), concatenated flat f32.
//
// Round-8: exp-precompute. tanh identity: la·tanh(x) sum = Sla - sum la2/(1+e^{2x}),
// and e^{2x} = Eq*Ek with Eq=exp2(ALPHA*aq), Ek=exp2(ALPHA*(ak+bias)) computed in
// the GEMM epilogue. Fused hot loop: acc += la2 * rcp(fma(Eq,Ek,1)) -> 3 VALU,
// 1 trans per element (was 5 VALU, 2 trans). Wave-uniform per-n values packed
// into one LDS float4 (1 ds_read_b128/iter, was 3 ds_read_b32).
//
//  K0 cast+prep: q/k/Wq/Wk -> bf16; la2 = 2*la_n, Sla = sum(la_n)
//  K1 gemm:  aqE[q][n]  = exp2(ALPHA*(query@Wq^T))            (1024x1024)
//            akE[n][bk] = exp2(ALPHA*(Wk@keys^T + bias[n]))   (1024x2048)
//  K2 fused: scores = Sla - sum_n la2[n]*rcp(1+Eq*Ek); softmax; ctx = p@keys

#define ALPHA_2LOG2E 2.8853900817779268f
#define LOG2E 1.4426950408889634f

typedef __attribute__((ext_vector_type(8))) short short8;
typedef __attribute__((ext_vector_type(4))) float f32x4;

static __device__ __forceinline__ short f2bf(float f) {
    union { float f; unsigned u; } v; v.f = f;
    unsigned r = v.u + 0x7fffu + ((v.u >> 16) & 1u);   // round-nearest-even
    return (short)(r >> 16);
}

// ---------------- K0: fp32 -> bf16 cast, plus la prep in last block ----------------
__global__ __launch_bounds__(256) void cast_prep_kernel(
    const float* __restrict__ q, const float* __restrict__ k,
    const float* __restrict__ wq, const float* __restrict__ wk,
    short* __restrict__ qb, short* __restrict__ kb,
    short* __restrict__ wqb, short* __restrict__ wkb,
    const float* __restrict__ la, const float* __restrict__ scal,
    float* __restrict__ la2, float* __restrict__ sla)
{
    const int bid = blockIdx.x;
    if (bid == 2560) {   // la prep
        __shared__ float red[4];
        const int t = threadIdx.x, lane = t & 63, w = t >> 6;
        float ss = 0.f;
        for (int i = t; i < 1024; i += 256) { float v = la[i]; ss = fmaf(v, v, ss); }
        #pragma unroll
        for (int off = 32; off; off >>= 1) ss += __shfl_xor(ss, off, 64);
        if (lane == 0) red[w] = ss;
        __syncthreads();
        const float tot = red[0] + red[1] + red[2] + red[3];
        const float sc = scal[0] / sqrtf(tot);
        float s2 = 0.f;
        for (int i = t; i < 1024; i += 256) {
            float v = la[i] * sc;
            la2[i] = 2.f * v;
            s2 += v;
        }
        #pragma unroll
        for (int off = 32; off; off >>= 1) s2 += __shfl_xor(s2, off, 64);
        __syncthreads();
        if (lane == 0) red[w] = s2;
        __syncthreads();
        if (t == 0) sla[0] = red[0] + red[1] + red[2] + red[3];
        return;
    }
    const float* src; short* dst; int base;
    if (bid < 512)       { src = q;  dst = qb;  base = bid; }
    else if (bid < 1536) { src = k;  dst = kb;  base = bid - 512; }
    else if (bid < 2048) { src = wq; dst = wqb; base = bid - 1536; }
    else                 { src = wk; dst = wkb; base = bid - 2048; }
    const size_t i = ((size_t)base * 256 + threadIdx.x) * 8;
    float4 a = *reinterpret_cast<const float4*>(src + i);
    float4 b = *reinterpret_cast<const float4*>(src + i + 4);
    short8 o;
    o[0] = f2bf(a.x); o[1] = f2bf(a.y); o[2] = f2bf(a.z); o[3] = f2bf(a.w);
    o[4] = f2bf(b.x); o[5] = f2bf(b.y); o[6] = f2bf(b.z); o[7] = f2bf(b.w);
    *reinterpret_cast<short8*>(dst + i) = o;
}

// ---------------- K1: bf16 MFMA NT-GEMM with exp2 epilogue ----------------
// bid < 128 : aqE = exp2(ALPHA*(qb @ wqb^T)),           C 1024x1024 (ldc 1024)
// bid >= 128: akE = exp2(ALPHA*(wkb @ kb^T + bias[m])), C 1024x2048 (ldc 2048)
__global__ __launch_bounds__(256) void gemm_mfma_kernel(
    const short* __restrict__ qb, const short* __restrict__ kb,
    const short* __restrict__ wqb, const short* __restrict__ wkb,
    const float* __restrict__ bias,
    float* __restrict__ aqE, float* __restrict__ akE)
{
    __shared__ short As[2][128][32];
    __shared__ short Bs[2][64][32];

    const int bid = blockIdx.x;
    const short* A; const short* W; float* C; int useBias, bm, bn, ldc;
    if (bid < 128) {
        A = qb;  W = wqb; C = aqE; useBias = 0; ldc = 1024;
        bm = (bid & 7) * 128; bn = (bid >> 3) * 64;
    } else {
        int b2 = bid - 128;
        A = wkb; W = kb;  C = akE; useBias = 1; ldc = 2048;
        bm = (b2 & 7) * 128; bn = (b2 >> 3) * 64;
    }

    const int t = threadIdx.x;
    const int lane = t & 63, wid = t >> 6;
    const int wr = wid >> 1, wc = wid & 1;
    const int fr = lane & 15, fg = lane >> 4;

    const int sRow = t >> 2, sSlot = t & 3;
    const short8* pA = (const short8*)(A + (size_t)bm * 1024);
    const short8* pB = (const short8*)(W + (size_t)bn * 1024);

    const f32x4 zero = {0.f, 0.f, 0.f, 0.f};
    f32x4 acc[4][2];
    #pragma unroll
    for (int mi = 0; mi < 4; ++mi)
        #pragma unroll
        for (int ni = 0; ni < 2; ++ni) acc[mi][ni] = zero;

    short8 rA0 = pA[(size_t)sRow * 128 + sSlot];
    short8 rA1 = pA[(size_t)(sRow + 64) * 128 + sSlot];
    short8 rB  = pB[(size_t)sRow * 128 + sSlot];
    *(short8*)&As[0][sRow][sSlot * 8]      = rA0;
    *(short8*)&As[0][sRow + 64][sSlot * 8] = rA1;
    *(short8*)&Bs[0][sRow][sSlot * 8]      = rB;
    rA0 = pA[(size_t)sRow * 128 + 4 + sSlot];
    rA1 = pA[(size_t)(sRow + 64) * 128 + 4 + sSlot];
    rB  = pB[(size_t)sRow * 128 + 4 + sSlot];
    asm volatile("s_waitcnt lgkmcnt(0)" ::: "memory");
    __builtin_amdgcn_s_barrier();
    asm volatile("" ::: "memory");

    #pragma unroll 1
    for (int kt = 0; kt < 32; ++kt) {
        const int cur = kt & 1;
        short8 af[4], bfr[2];
        #pragma unroll
        for (int mi = 0; mi < 4; ++mi)
            af[mi] = *(const short8*)&As[cur][wr * 64 + mi * 16 + fr][fg * 8];
        #pragma unroll
        for (int ni = 0; ni < 2; ++ni)
            bfr[ni] = *(const short8*)&Bs[cur][wc * 32 + ni * 16 + fr][fg * 8];
        if (kt < 31) {
            *(short8*)&As[cur ^ 1][sRow][sSlot * 8]      = rA0;
            *(short8*)&As[cur ^ 1][sRow + 64][sSlot * 8] = rA1;
            *(short8*)&Bs[cur ^ 1][sRow][sSlot * 8]      = rB;
        }
        if (kt < 30) {
            const int koff = (kt + 2) * 4 + sSlot;
            rA0 = pA[(size_t)sRow * 128 + koff];
            rA1 = pA[(size_t)(sRow + 64) * 128 + koff];
            rB  = pB[(size_t)sRow * 128 + koff];
        }
        #pragma unroll
        for (int mi = 0; mi < 4; ++mi)
            #pragma unroll
            for (int ni = 0; ni < 2; ++ni)
                acc[mi][ni] = __builtin_amdgcn_mfma_f32_16x16x32_bf16(
                    af[mi], bfr[ni], acc[mi][ni], 0, 0, 0);
        asm volatile("s_waitcnt lgkmcnt(0)" ::: "memory");
        __builtin_amdgcn_s_barrier();
        asm volatile("" ::: "memory");
    }

    // C/D: col=lane&15, row=(lane>>4)*4+reg  [m89-verified]; epilogue: exp2(ALPHA*(v+bias))
    float* Cb = C + (size_t)bm * ldc;
    #pragma unroll
    for (int mi = 0; mi < 4; ++mi) {
        const int row0 = wr * 64 + mi * 16 + fg * 4;
        float brow[4] = {0.f, 0.f, 0.f, 0.f};
        if (useBias) {
            #pragma unroll
            for (int r = 0; r < 4; ++r) brow[r] = bias[bm + row0 + r];
        }
        #pragma unroll
        for (int ni = 0; ni < 2; ++ni) {
            const int col = bn + wc * 32 + ni * 16 + fr;
            #pragma unroll
            for (int r = 0; r < 4; ++r)
                Cb[(size_t)(row0 + r) * ldc + col] =
                    __builtin_amdgcn_exp2f((acc[mi][ni][r] + brow[r]) * ALPHA_2LOG2E);
        }
    }
}

// ---------------- K2: fused scores + softmax + context (exp-precomputed) ----------------
// grid (16 batch, 32 q-pairs), 512 threads (8 waves). Lane owns k = {2l, 2l+1}.
// Wave w accumulates n in [128w, 128w+128). Hot loop per n:
//   1 ds_read_b128 (la2, Eq0, Eq1), 1 global dwordx2 (Ek pair),
//   4x { fma(Eq,Ek,1); rcp; fma(la2, r, acc) }  -- no cross-lane ops.
__global__ __launch_bounds__(512) void fused_kernel(
    const float* __restrict__ aqE, const float* __restrict__ akE,
    const float* __restrict__ la2, const float* __restrict__ sla,
    const float* __restrict__ keys,
    float* __restrict__ ctx, float* __restrict__ out_scores)
{
    const int b = blockIdx.x;
    const int q0 = blockIdx.y << 1;
    const int t = threadIdx.x;
    const int w = t >> 6, lane = t & 63;

    __shared__ float4 s4[1024];         // 16 KB: {la2[n], Eq[q0][n], Eq[q0+1][n], pad}
    __shared__ float pacc[8][2][128];   // 8 KB
    __shared__ float p_s[2][128];       // 1 KB

    // stage packed per-n uniforms
    {
        const float* e0p = aqE + ((size_t)((b << 6) + q0) << 10);
        const float* e1p = e0p + 1024;
        #pragma unroll
        for (int i = 0; i < 2; ++i) {
            const int n = t + (i << 9);
            float4 v = {la2[n], e0p[n], e1p[n], 0.f};
            s4[n] = v;
        }
    }
    __syncthreads();

    // scores partials
    float acc[2][2];
    acc[0][0] = acc[0][1] = acc[1][0] = acc[1][1] = 0.f;

    const float* akb = akE + (b << 7) + (lane << 1);   // row stride 2048 floats
    const int nbase = w << 7;
    #pragma unroll 8
    for (int n = 0; n < 128; ++n) {
        const int nn = nbase + n;
        const float2 ek = *reinterpret_cast<const float2*>(akb + ((size_t)nn << 11));
        const float4 s = s4[nn];        // broadcast: la2, Eq0, Eq1
        const float r00 = __builtin_amdgcn_rcpf(fmaf(s.y, ek.x, 1.f));
        const float r01 = __builtin_amdgcn_rcpf(fmaf(s.y, ek.y, 1.f));
        const float r10 = __builtin_amdgcn_rcpf(fmaf(s.z, ek.x, 1.f));
        const float r11 = __builtin_amdgcn_rcpf(fmaf(s.z, ek.y, 1.f));
        acc[0][0] = fmaf(s.x, r00, acc[0][0]);
        acc[0][1] = fmaf(s.x, r01, acc[0][1]);
        acc[1][0] = fmaf(s.x, r10, acc[1][0]);
        acc[1][1] = fmaf(s.x, r11, acc[1][1]);
    }
    #pragma unroll
    for (int q = 0; q < 2; ++q) {
        float2 v = {acc[q][0], acc[q][1]};
        *reinterpret_cast<float2*>(&pacc[w][q][lane << 1]) = v;
    }
    __syncthreads();

    // softmax: wave w<2 handles q-row w (lane holds k=2l,2l+1)
    if (w < 2) {
        const float Sla = sla[0];
        float s0 = 0.f, s1 = 0.f;
        #pragma unroll
        for (int ww = 0; ww < 8; ++ww) {
            float2 v = *reinterpret_cast<const float2*>(&pacc[ww][w][lane << 1]);
            s0 += v.x; s1 += v.y;
        }
        s0 = Sla - s0; s1 = Sla - s1;
        float m = fmaxf(s0, s1);
        #pragma unroll
        for (int off = 32; off; off >>= 1) m = fmaxf(m, __shfl_xor(m, off, 64));
        float e0 = __builtin_amdgcn_exp2f((s0 - m) * LOG2E);
        float e1 = __builtin_amdgcn_exp2f((s1 - m) * LOG2E);
        float s = e0 + e1;
        #pragma unroll
        for (int off = 32; off; off >>= 1) s += __shfl_xor(s, off, 64);
        const float inv = __builtin_amdgcn_rcpf(s);
        float2 p = {e0 * inv, e1 * inv};
        *reinterpret_cast<float2*>(&p_s[w][lane << 1]) = p;
        float* os = out_scores + ((size_t)((b << 6) + q0 + w) << 7);
        *reinterpret_cast<float2*>(os + (lane << 1)) = p;
    }
    __syncthreads();

    // context: thread t -> cols n0,n0+1 for both q-rows
    const int n0 = t << 1;
    const float* kb = keys + ((size_t)(b << 7) << 10) + n0;
    float c00 = 0.f, c01 = 0.f, c10 = 0.f, c11 = 0.f;
    #pragma unroll 4
    for (int k = 0; k < 128; ++k) {
        const float2 kv = *reinterpret_cast<const float2*>(kb + ((size_t)k << 10));
        const float p0 = p_s[0][k], p1 = p_s[1][k];
        c00 = fmaf(p0, kv.x, c00); c01 = fmaf(p0, kv.y, c01);
        c10 = fmaf(p1, kv.x, c10); c11 = fmaf(p1, kv.y, c11);
    }
    float* cp = ctx + ((size_t)((b << 6) + q0) << 10) + n0;
    float2 o0 = {c00, c01}, o1 = {c10, c11};
    *reinterpret_cast<float2*>(cp) = o0;
    *reinterpret_cast<float2*>(cp + 1024) = o1;
}

extern "C" void kernel_launch(void* const* d_in, const int* in_sizes, int n_in,
                              void* d_out, int out_size, void* d_ws, size_t ws_size,
                              hipStream_t stream) {
    const float* query  = (const float*)d_in[0];
    const float* keys   = (const float*)d_in[1];
    const float* Wq     = (const float*)d_in[2];
    const float* Wk     = (const float*)d_in[3];
    const float* la     = (const float*)d_in[4];
    const float* scal   = (const float*)d_in[5];
    const float* bias   = (const float*)d_in[6];

    float* ws  = (float*)d_ws;
    float* aqE = ws;                        // 1M f32 (4 MB), [1024 q][1024 n] = exp2 vals
    float* akE = ws + (1u << 20);           // 2M f32 (8 MB), [1024 n][2048 bk] = exp2 vals
    float* la2 = akE + (2u << 20);          // 1024 f32
    float* sla = la2 + 1024;                // 1 f32
    short* qb  = (short*)(ws + 3 * 1048576 + 2048);  // 1M bf16
    short* kb  = qb + 1048576;                       // 2M bf16
    short* wqb = kb + 2097152;                       // 1M bf16
    short* wkb = wqb + 1048576;                      // 1M bf16

    float* ctx        = (float*)d_out;
    float* out_scores = ctx + (size_t)16 * 64 * 1024;

    cast_prep_kernel<<<2561, 256, 0, stream>>>(query, keys, Wq, Wk, qb, kb, wqb, wkb,
                                               la, scal, la2, sla);
    gemm_mfma_kernel<<<384, 256, 0, stream>>>(qb, kb, wqb, wkb, bias, aqE, akE);
    fused_kernel<<<dim3(16, 32), 512, 0, stream>>>(aqE, akE, la2, sla, keys, ctx, out_scores);
}